// Round 1
// baseline (2090.373 us; speedup 1.0000x reference)
//
#include <hip/hip_runtime.h>
#include <stdint.h>
#include <stddef.h>

#define DM 768

typedef __attribute__((ext_vector_type(8))) short short8;
typedef __attribute__((ext_vector_type(4))) short short4v;
typedef __attribute__((ext_vector_type(4))) float floatx4;

__device__ __forceinline__ short f2bf(float f) {
    union { float f; uint32_t u; } v; v.f = f;
    uint32_t u = v.u + 0x7fffu + ((v.u >> 16) & 1u);
    return (short)(u >> 16);
}

// ---------------- cast fp32 -> bf16 (weights) ----------------
__global__ __launch_bounds__(256) void cast_w_kernel(const float* __restrict__ src,
                                                     short* __restrict__ dst, int n4) {
    int i = blockIdx.x * blockDim.x + threadIdx.x;
    if (i < n4) {
        float4 v = ((const float4*)src)[i];
        short4v o;
        o.x = f2bf(v.x); o.y = f2bf(v.y); o.z = f2bf(v.z); o.w = f2bf(v.w);
        ((short4v*)dst)[i] = o;
    }
}

// ---------------- projection: Y = X @ W^T + b, bf16 out (row-major + transposed) ----
// grid: (rows/16, 12). block 256 (4 waves). Each wave does a 16x16 col chunk.
__global__ __launch_bounds__(256) void proj_kernel(
    const float* __restrict__ X,   // (B*L, 768) fp32
    const short* __restrict__ Wb,  // (768, 768) bf16, row-major (W[col][k])
    const float* __restrict__ bias,
    short* __restrict__ Y,         // (B*L, 768) bf16
    short* __restrict__ Yt,        // (B, 768, L) bf16
    int L)
{
    __shared__ short Xs[16 * 776];   // padded row stride 776 (16B aligned rows)
    const int row0 = blockIdx.x * 16;
    const int cb   = blockIdx.y;
    const int tid  = threadIdx.x;

    {   // stage X tile (fp32 -> bf16)
        const int rr = tid >> 4;
        const int c0 = (tid & 15) * 4;
        const float* xp = X + (size_t)(row0 + rr) * DM + c0;
        short* sp = Xs + rr * 776 + c0;
#pragma unroll
        for (int it = 0; it < 12; ++it) {
            float4 v = *(const float4*)(xp + it * 64);
            sp[it * 64 + 0] = f2bf(v.x);
            sp[it * 64 + 1] = f2bf(v.y);
            sp[it * 64 + 2] = f2bf(v.z);
            sp[it * 64 + 3] = f2bf(v.w);
        }
    }
    __syncthreads();

    const int w = tid >> 6, l = tid & 63, r = l & 15, q = l >> 4;
    const int col = cb * 64 + w * 16 + r;

    floatx4 acc = {0.f, 0.f, 0.f, 0.f};
    const short* wrow = Wb + (size_t)col * DM + q * 8;
    const short* xrow = Xs + r * 776 + q * 8;
#pragma unroll
    for (int k = 0; k < DM; k += 32) {
        short8 a = *(const short8*)(xrow + k);
        short8 b = *(const short8*)(wrow + k);
        acc = __builtin_amdgcn_mfma_f32_16x16x32_bf16(a, b, acc, 0, 0, 0);
    }

    const float bv = bias[col];
    const int b_   = row0 / L;          // L is a multiple of 16: tiles never straddle batches
    const int pos0 = row0 - b_ * L;
    short4v tv;
#pragma unroll
    for (int i = 0; i < 4; ++i) {
        short hv = f2bf(acc[i] + bv);   // lane holds D[q*4+i][r]
        Y[(size_t)(row0 + q * 4 + i) * DM + col] = hv;
        tv[i] = hv;
    }
    *(short4v*)(Yt + (size_t)(b_ * DM + col) * L + pos0 + q * 4) = tv;
}

// ---------------- fused cross-attention ----------------
// Out[b, row0:row0+16, :] = sum over 2 KV sources of softmax(Q Ks^T/8 + bias_s) Vs
// grid: (R/16, B). block 256 (4 waves).
__global__ __launch_bounds__(256, 2) void attn_kernel(
    const short* __restrict__ Q,                                   // (B,R,768) bf16
    const short* __restrict__ K0, const short* __restrict__ V0,    // K:(B,C0,768)  V:(B,768,C0)
    const float* __restrict__ M0, int C0,
    const short* __restrict__ K1, const short* __restrict__ V1,
    const float* __restrict__ M1, int C1,
    float* __restrict__ Out, int R, int Sstride, int Pstride)
{
    extern __shared__ char lds[];
    float* S = (float*)lds;                              // 16 x Sstride fp32
    short* P = (short*)(lds + (size_t)16 * Sstride * 4); // 16 x Pstride bf16

    const int b    = blockIdx.y;
    const int row0 = blockIdx.x * 16;
    const int tid  = threadIdx.x;
    const int w = tid >> 6, l = tid & 63, r = l & 15, q = l >> 4;

    // Preload all Q A-fragments for this lane (row row0+r, k = 32t + q*8 .. +8)
    short8 qf[24];
    {
        const short* qp = Q + ((size_t)b * R + row0 + r) * DM + q * 8;
#pragma unroll
        for (int t = 0; t < 24; ++t) qf[t] = *(const short8*)(qp + t * 32);
    }

    floatx4 o[12];
#pragma unroll
    for (int i = 0; i < 12; ++i) o[i] = (floatx4){0.f, 0.f, 0.f, 0.f};

    for (int s = 0; s < 2; ++s) {
        const short* Kp = s ? K1 : K0;
        const short* Vp = s ? V1 : V0;
        const int C     = s ? C1 : C0;
        const float* mp = (s ? M1 : M0) + (size_t)b * C;

        // -------- phase A: S = Q K^T / 8 + mask bias --------
        for (int j0 = w * 16; j0 < C; j0 += 64) {
            floatx4 acc = {0.f, 0.f, 0.f, 0.f};
            const short* kp = Kp + ((size_t)b * C + j0 + r) * DM + q * 8;
#pragma unroll
            for (int t = 0; t < 24; ++t) {
                short8 bb = *(const short8*)(kp + t * 32);
                acc = __builtin_amdgcn_mfma_f32_16x16x32_bf16(qf[t], bb, acc, 0, 0, 0);
            }
            const int j = j0 + r;
            const float mv = mp[j];
#pragma unroll
            for (int i = 0; i < 4; ++i) {
                const int gi = row0 + q * 4 + i;
                const bool allowed = (j < C - 64) ||
                    ((gi >= R - 64) && ((j - (C - 64)) <= (gi - (R - 64))));
                const float am = allowed ? mv : 0.f;
                // (1 - am)*(-10000) == (am - 1)*10000
                S[(q * 4 + i) * Sstride + j] = acc[i] * 0.125f + (am - 1.f) * 10000.f;
            }
        }
        __syncthreads();

        // -------- softmax (16 threads per row) --------
        {
            const int row = tid >> 4, pp = tid & 15;
            float* srow = S + row * Sstride;
            float mx = -3.0e38f;
            for (int j = pp; j < C; j += 16) mx = fmaxf(mx, srow[j]);
#pragma unroll
            for (int d = 1; d < 16; d <<= 1) mx = fmaxf(mx, __shfl_xor(mx, d, 16));
            float sum = 0.f;
            for (int j = pp; j < C; j += 16) {
                float e = __expf(srow[j] - mx);
                srow[j] = e;
                sum += e;
            }
#pragma unroll
            for (int d = 1; d < 16; d <<= 1) sum += __shfl_xor(sum, d, 16);
            const float inv = 1.f / sum;
            short* prow = P + row * Pstride;
            for (int j = pp; j < C; j += 16) prow[j] = f2bf(srow[j] * inv);
        }
        __syncthreads();

        // -------- phase B: O += P @ V (V stored transposed: (768, C)) --------
        {
            const short* prow  = P + r * Pstride + q * 8;
            const short* vbase = Vp + ((size_t)b * DM + w * 192 + r) * (size_t)C + q * 8;
            for (int kc = 0; kc < C; kc += 32) {
                short8 a = *(const short8*)(prow + kc);
#pragma unroll
                for (int cc = 0; cc < 12; ++cc) {
                    short8 bb = *(const short8*)(vbase + (size_t)cc * 16 * C + kc);
                    o[cc] = __builtin_amdgcn_mfma_f32_16x16x32_bf16(a, bb, o[cc], 0, 0, 0);
                }
            }
        }
        __syncthreads();
    }

    // -------- epilogue: write fp32 output --------
#pragma unroll
    for (int cc = 0; cc < 12; ++cc) {
        const int d0 = w * 192 + cc * 16 + r;
        float* op = Out + ((size_t)b * R + row0 + q * 4) * DM + d0;
#pragma unroll
        for (int i = 0; i < 4; ++i) op[(size_t)i * DM] = o[cc][i];
    }
}

// ---------------- host ----------------
extern "C" void kernel_launch(void* const* d_in, const int* in_sizes, int n_in,
                              void* d_out, int out_size, void* d_ws, size_t ws_size,
                              hipStream_t stream) {
    const float* vidX = (const float*)d_in[0];
    const float* mV   = (const float*)d_in[1];
    const float* detX = (const float*)d_in[2];
    const float* mD   = (const float*)d_in[3];
    const float* actX = (const float*)d_in[4];
    const float* mA   = (const float*)d_in[5];
    const float* Wv   = (const float*)d_in[6];
    const float* bv   = (const float*)d_in[7];
    const float* Wd   = (const float*)d_in[8];
    const float* bd   = (const float*)d_in[9];
    const float* Wa   = (const float*)d_in[10];
    const float* ba   = (const float*)d_in[11];

    // workspace layout (shorts): 3x W bf16, 3x Y bf16, 3x Yt bf16  (~217 MB total)
    short* p = (short*)d_ws;
    short* Wvb  = p; p += 589824;
    short* Wdb  = p; p += 589824;
    short* Wab  = p; p += 589824;
    short* vidY = p; p += 28311552;   // 64*576*768
    short* detY = p; p += 15728640;   // 64*320*768
    short* actY = p; p += 9437184;    // 64*192*768
    short* vidT = p; p += 28311552;
    short* detT = p; p += 15728640;
    short* actT = p; p += 9437184;

    float* o0 = (float*)d_out;            // (64,576,768)
    float* o1 = o0 + 28311552;            // (64,320,768)
    float* o2 = o1 + 15728640;            // (64,192,768)

    cast_w_kernel<<<576, 256, 0, stream>>>(Wv, Wvb, 147456);
    cast_w_kernel<<<576, 256, 0, stream>>>(Wd, Wdb, 147456);
    cast_w_kernel<<<576, 256, 0, stream>>>(Wa, Wab, 147456);

    proj_kernel<<<dim3(2304, 12), 256, 0, stream>>>(vidX, Wvb, bv, vidY, vidT, 576);
    proj_kernel<<<dim3(1280, 12), 256, 0, stream>>>(detX, Wdb, bd, detY, detT, 320);
    proj_kernel<<<dim3(768,  12), 256, 0, stream>>>(actX, Wab, ba, actY, actT, 192);

    // out0 = attn(vid | det) + attn(vid | act): Cmax=320 -> Sstride 321, Pstride 328
    attn_kernel<<<dim3(36, 64), 256, 31040, stream>>>(
        vidY, detY, detT, mD, 320, actY, actT, mA, 192, o0, 576, 321, 328);
    // out1 = attn(det | vid) + attn(det | act): Cmax=576 -> Sstride 577, Pstride 584
    attn_kernel<<<dim3(20, 64), 256, 55616, stream>>>(
        detY, vidY, vidT, mV, 576, actY, actT, mA, 192, o1, 320, 577, 584);
    // out2 = attn(act | vid) + attn(act | det)
    attn_kernel<<<dim3(12, 64), 256, 55616, stream>>>(
        actY, vidY, vidT, mV, 576, detY, detT, mD, 320, o2, 192, 577, 584);
}

// Round 2
// 1247.419 us; speedup vs baseline: 1.6758x; 1.6758x over previous
//
#include <hip/hip_runtime.h>
#include <stdint.h>
#include <stddef.h>

typedef __attribute__((ext_vector_type(8))) short short8;
typedef __attribute__((ext_vector_type(4))) short short4v;
typedef __attribute__((ext_vector_type(4))) float floatx4;

__device__ __forceinline__ short f2bf(float f) {
    union { float f; uint32_t u; } v; v.f = f;
    uint32_t u = v.u + 0x7fffu + ((v.u >> 16) & 1u);
    return (short)(u >> 16);
}

__device__ __forceinline__ void async16(short* lds, const short* g) {
    __builtin_amdgcn_global_load_lds(
        (const __attribute__((address_space(1))) unsigned int*)g,
        (__attribute__((address_space(3))) unsigned int*)lds, 16, 0, 0);
}

// stage a 128-row x 32-col bf16 tile into LDS (row-major, no pad — lane-ordered for global_load_lds)
// src points at (row0, k0); ld = row stride in elements. Each thread moves 2x16B.
__device__ __forceinline__ void stage128x32(short* lds, const short* src, size_t ld, int t) {
    const short* g = src + (size_t)(t >> 2) * ld + (t & 3) * 8;
    async16(lds + t * 8, g);
    async16(lds + 2048 + t * 8, g + 64 * ld);
}

// ---------------- fp32 -> bf16 cast ----------------
__global__ __launch_bounds__(256) void cast_kernel(const float* __restrict__ src,
                                                   short* __restrict__ dst, int n4) {
    int i = blockIdx.x * blockDim.x + threadIdx.x;
    if (i < n4) {
        float4 v = ((const float4*)src)[i];
        short4v o;
        o.x = f2bf(v.x); o.y = f2bf(v.y); o.z = f2bf(v.z); o.w = f2bf(v.w);
        ((short4v*)dst)[i] = o;
    }
}

// ---------------- projection GEMM: Y = X @ W^T + b (dual store: Y and Yt) ----------------
// A: (M,768) bf16, W: (768,768) bf16 row-major (B[n][k]). M = 64*L, exact 128-tiles.
__global__ __launch_bounds__(256) void proj_gemm(
    const short* __restrict__ A, const short* __restrict__ W,
    const float* __restrict__ bias,
    short* __restrict__ Y, short* __restrict__ Yt, int L)
{
    __shared__ short As[4096], Bs[4096];
    const int t = threadIdx.x, w = t >> 6, l = t & 63;
    const int wr = (w >> 1) * 64, wc = (w & 1) * 64, lr = l & 15, lq = l >> 4;
    const size_t m0 = (size_t)blockIdx.x * 128;
    const int n0 = blockIdx.y * 128;
    const short* Ab = A + m0 * 768;
    const short* Bb = W + (size_t)n0 * 768;

    floatx4 acc[4][4];
#pragma unroll
    for (int i = 0; i < 4; ++i)
#pragma unroll
        for (int j = 0; j < 4; ++j) acc[i][j] = (floatx4){0.f, 0.f, 0.f, 0.f};

    for (int k0 = 0; k0 < 768; k0 += 32) {
        stage128x32(As, Ab + k0, 768, t);
        stage128x32(Bs, Bb + k0, 768, t);
        __syncthreads();
        short8 af[4], bf[4];
#pragma unroll
        for (int i = 0; i < 4; ++i) af[i] = *(const short8*)(As + (wr + i * 16 + lr) * 32 + lq * 8);
#pragma unroll
        for (int j = 0; j < 4; ++j) bf[j] = *(const short8*)(Bs + (wc + j * 16 + lr) * 32 + lq * 8);
#pragma unroll
        for (int i = 0; i < 4; ++i)
#pragma unroll
            for (int j = 0; j < 4; ++j)
                acc[i][j] = __builtin_amdgcn_mfma_f32_16x16x32_bf16(af[i], bf[j], acc[i][j], 0, 0, 0);
        __syncthreads();
    }

#pragma unroll
    for (int i = 0; i < 4; ++i) {
        const int mb = (int)m0 + wr + i * 16 + lq * 4;
        const int b_ = mb / L, pos = mb - b_ * L;
#pragma unroll
        for (int j = 0; j < 4; ++j) {
            const int n = n0 + wc + j * 16 + lr;
            const float bv = bias[n];
            short4v tv;
#pragma unroll
            for (int r2 = 0; r2 < 4; ++r2) {
                short hv = f2bf(acc[i][j][r2] + bv);
                Y[(size_t)(mb + r2) * 768 + n] = hv;
                tv[r2] = hv;
            }
            *(short4v*)(Yt + ((size_t)b_ * 768 + n) * L + pos) = tv;
        }
    }
}

// ---------------- S GEMM: S = Q K^T * 0.125 + mask bias (batched, fp32 out) ----------------
__global__ __launch_bounds__(256) void s_gemm(
    const short* __restrict__ Q, const short* __restrict__ K,
    const float* __restrict__ mask, float* __restrict__ S, int R, int C)
{
    __shared__ short As[4096], Bs[4096];
    const int t = threadIdx.x, w = t >> 6, l = t & 63;
    const int wr = (w >> 1) * 64, wc = (w & 1) * 64, lr = l & 15, lq = l >> 4;
    const int b = blockIdx.z;
    const int m0 = blockIdx.x * 128, n0 = blockIdx.y * 128;
    const short* Ab = Q + ((size_t)b * R + m0) * 768;
    const short* Bb = K + ((size_t)b * C + n0) * 768;

    floatx4 acc[4][4];
#pragma unroll
    for (int i = 0; i < 4; ++i)
#pragma unroll
        for (int j = 0; j < 4; ++j) acc[i][j] = (floatx4){0.f, 0.f, 0.f, 0.f};

    for (int k0 = 0; k0 < 768; k0 += 32) {
        stage128x32(As, Ab + k0, 768, t);
        stage128x32(Bs, Bb + k0, 768, t);
        __syncthreads();
        short8 af[4], bf[4];
#pragma unroll
        for (int i = 0; i < 4; ++i) af[i] = *(const short8*)(As + (wr + i * 16 + lr) * 32 + lq * 8);
#pragma unroll
        for (int j = 0; j < 4; ++j) bf[j] = *(const short8*)(Bs + (wc + j * 16 + lr) * 32 + lq * 8);
#pragma unroll
        for (int i = 0; i < 4; ++i)
#pragma unroll
            for (int j = 0; j < 4; ++j)
                acc[i][j] = __builtin_amdgcn_mfma_f32_16x16x32_bf16(af[i], bf[j], acc[i][j], 0, 0, 0);
        __syncthreads();
    }

    const int Rm = R - 64, Cm = C - 64;
#pragma unroll
    for (int j = 0; j < 4; ++j) {
        const int n = n0 + wc + j * 16 + lr;
        if (n >= C) continue;
        const float mv = mask[(size_t)b * C + n];
#pragma unroll
        for (int i = 0; i < 4; ++i) {
            const int mb = m0 + wr + i * 16 + lq * 4;
#pragma unroll
            for (int r2 = 0; r2 < 4; ++r2) {
                const int mm = mb + r2;
                if (mm < R) {
                    const bool allowed = (n < Cm) || ((mm >= Rm) && ((n - Cm) <= (mm - Rm)));
                    const float am = allowed ? mv : 0.f;
                    S[((size_t)b * R + mm) * C + n] = acc[i][j][r2] * 0.125f + (am - 1.f) * 10000.f;
                }
            }
        }
    }
}

// ---------------- softmax: P = softmax_row(S), bf16 out. one wave per row ----------------
__global__ __launch_bounds__(256) void softmax_k(const float* __restrict__ S,
                                                 short* __restrict__ P, int C) {
    const int row = blockIdx.x * 4 + (threadIdx.x >> 6);
    const int l = threadIdx.x & 63;
    const float* s = S + (size_t)row * C;
    float v[9];
    int cnt = 0;
    float mx = -3.0e38f;
    for (int j = l; j < C; j += 64) { float x = s[j]; v[cnt++] = x; mx = fmaxf(mx, x); }
#pragma unroll
    for (int d = 32; d; d >>= 1) mx = fmaxf(mx, __shfl_xor(mx, d, 64));
    float sum = 0.f;
    for (int i = 0; i < cnt; ++i) { v[i] = __expf(v[i] - mx); sum += v[i]; }
#pragma unroll
    for (int d = 32; d; d >>= 1) sum += __shfl_xor(sum, d, 64);
    const float inv = 1.f / sum;
    short* p = P + (size_t)row * C;
    cnt = 0;
    for (int j = l; j < C; j += 64) p[j] = f2bf(v[cnt++] * inv);
}

// ---------------- PV GEMM: O = P0 @ V0 + P1 @ V1 (fp32 out), V given transposed (768,C) ----
__global__ __launch_bounds__(256) void pv_gemm(
    const short* __restrict__ P0, const short* __restrict__ Vt0, int C0,
    const short* __restrict__ P1, const short* __restrict__ Vt1, int C1,
    float* __restrict__ O, int R)
{
    __shared__ short As[4096], Bs[4096];
    const int t = threadIdx.x, w = t >> 6, l = t & 63;
    const int wr = (w >> 1) * 64, wc = (w & 1) * 64, lr = l & 15, lq = l >> 4;
    const int b = blockIdx.z;
    const int m0 = blockIdx.x * 128, n0 = blockIdx.y * 128;

    floatx4 acc[4][4];
#pragma unroll
    for (int i = 0; i < 4; ++i)
#pragma unroll
        for (int j = 0; j < 4; ++j) acc[i][j] = (floatx4){0.f, 0.f, 0.f, 0.f};

    for (int s = 0; s < 2; ++s) {
        const short* Ab = (s ? P1 : P0);
        const short* Bb = (s ? Vt1 : Vt0);
        const int C = s ? C1 : C0;
        Ab += ((size_t)b * R + m0) * C;
        Bb += ((size_t)b * 768 + n0) * C;
        for (int k0 = 0; k0 < C; k0 += 32) {
            stage128x32(As, Ab + k0, C, t);
            stage128x32(Bs, Bb + k0, C, t);
            __syncthreads();
            short8 af[4], bf[4];
#pragma unroll
            for (int i = 0; i < 4; ++i) af[i] = *(const short8*)(As + (wr + i * 16 + lr) * 32 + lq * 8);
#pragma unroll
            for (int j = 0; j < 4; ++j) bf[j] = *(const short8*)(Bs + (wc + j * 16 + lr) * 32 + lq * 8);
#pragma unroll
            for (int i = 0; i < 4; ++i)
#pragma unroll
                for (int j = 0; j < 4; ++j)
                    acc[i][j] = __builtin_amdgcn_mfma_f32_16x16x32_bf16(af[i], bf[j], acc[i][j], 0, 0, 0);
            __syncthreads();
        }
    }

#pragma unroll
    for (int i = 0; i < 4; ++i) {
        const int mb = m0 + wr + i * 16 + lq * 4;
#pragma unroll
        for (int j = 0; j < 4; ++j) {
            const int n = n0 + wc + j * 16 + lr;
#pragma unroll
            for (int r2 = 0; r2 < 4; ++r2) {
                if (mb + r2 < R)
                    O[((size_t)b * R + mb + r2) * 768 + n] = acc[i][j][r2];
            }
        }
    }
}

// ---------------- host ----------------
extern "C" void kernel_launch(void* const* d_in, const int* in_sizes, int n_in,
                              void* d_out, int out_size, void* d_ws, size_t ws_size,
                              hipStream_t stream) {
    const float* vidX = (const float*)d_in[0];
    const float* mV   = (const float*)d_in[1];
    const float* detX = (const float*)d_in[2];
    const float* mD   = (const float*)d_in[3];
    const float* actX = (const float*)d_in[4];
    const float* mA   = (const float*)d_in[5];
    const float* Wv   = (const float*)d_in[6];
    const float* bv   = (const float*)d_in[7];
    const float* Wd   = (const float*)d_in[8];
    const float* bd   = (const float*)d_in[9];
    const float* Wa   = (const float*)d_in[10];
    const float* ba   = (const float*)d_in[11];

    const size_t EV = 28311552, ED = 15728640, EA = 9437184;   // elems per Y matrix
    char* p = (char*)d_ws;
    auto alloc = [&](size_t bytes) { char* r = p; p += (bytes + 255) & ~255ULL; return r; };

    short* Wvb = (short*)alloc(589824 * 2);
    short* Wdb = (short*)alloc(589824 * 2);
    short* Wab = (short*)alloc(589824 * 2);
    short* Yv  = (short*)alloc(EV * 2);
    short* Yd  = (short*)alloc(ED * 2);
    short* Ya  = (short*)alloc(EA * 2);
    short* Ytv = (short*)alloc(EV * 2);
    short* Ytd = (short*)alloc(ED * 2);
    short* Yta = (short*)alloc(EA * 2);
    // X bf16 region, later reused as the per-pair fp32 S buffer (max pair S = 47.2MB < 107MB)
    char* xs  = alloc((EV + ED + EA) * 2);
    short* Xv = (short*)xs;
    short* Xd = Xv + EV;
    short* Xa = Xd + ED;
    float* Sb = (float*)xs;
    short* Pvd = (short*)alloc((size_t)64 * 576 * 320 * 2);
    short* Pva = (short*)alloc((size_t)64 * 576 * 192 * 2);
    short* Pdv = (short*)alloc((size_t)64 * 320 * 576 * 2);
    short* Pda = (short*)alloc((size_t)64 * 320 * 192 * 2);
    short* Pav = (short*)alloc((size_t)64 * 192 * 576 * 2);
    short* Pad = (short*)alloc((size_t)64 * 192 * 320 * 2);
    (void)alloc(262144);   // slack for guarded-tile overhang reads

    float* o0 = (float*)d_out;
    float* o1 = o0 + EV;
    float* o2 = o1 + ED;

    // casts
    cast_kernel<<<576, 256, 0, stream>>>(Wv, Wvb, 147456);
    cast_kernel<<<576, 256, 0, stream>>>(Wd, Wdb, 147456);
    cast_kernel<<<576, 256, 0, stream>>>(Wa, Wab, 147456);
    cast_kernel<<<27648, 256, 0, stream>>>(vidX, Xv, (int)(EV / 4));
    cast_kernel<<<15360, 256, 0, stream>>>(detX, Xd, (int)(ED / 4));
    cast_kernel<<<9216, 256, 0, stream>>>(actX, Xa, (int)(EA / 4));

    // projections (M = 64*L, all exact multiples of 128)
    proj_gemm<<<dim3(288, 6), 256, 0, stream>>>(Xv, Wvb, bv, Yv, Ytv, 576);
    proj_gemm<<<dim3(160, 6), 256, 0, stream>>>(Xd, Wdb, bd, Yd, Ytd, 320);
    proj_gemm<<<dim3(96, 6), 256, 0, stream>>>(Xa, Wab, ba, Ya, Yta, 192);

    // per-pair S GEMM + softmax (S buffer reused serially)
    auto pair = [&](const short* Q, const short* K, const float* msk, short* Pout, int R, int C) {
        s_gemm<<<dim3((R + 127) / 128, (C + 127) / 128, 64), 256, 0, stream>>>(Q, K, msk, Sb, R, C);
        softmax_k<<<64 * R / 4, 256, 0, stream>>>(Sb, Pout, C);
    };
    pair(Yv, Yd, mD, Pvd, 576, 320);
    pair(Yv, Ya, mA, Pva, 576, 192);
    pair(Yd, Yv, mV, Pdv, 320, 576);
    pair(Yd, Ya, mA, Pda, 320, 192);
    pair(Ya, Yv, mV, Pav, 192, 576);
    pair(Ya, Yd, mD, Pad, 192, 320);

    // PV GEMMs (two sources accumulated)
    pv_gemm<<<dim3(5, 6, 64), 256, 0, stream>>>(Pvd, Ytd, 320, Pva, Yta, 192, o0, 576);
    pv_gemm<<<dim3(3, 6, 64), 256, 0, stream>>>(Pdv, Ytv, 576, Pda, Yta, 192, o1, 320);
    pv_gemm<<<dim3(2, 6, 64), 256, 0, stream>>>(Pav, Ytv, 576, Pad, Ytd, 320, o2, 192);
}